// Round 13
// baseline (2517.322 us; speedup 1.0000x reference)
//
#include <hip/hip_runtime.h>
#include <stdint.h>

#define N_NODES 50000
#define DIM_MEM 512
#define DIM_MSG 1280
#define N_MSG   100000

typedef __attribute__((ext_vector_type(8))) short bf16x8;
typedef __attribute__((ext_vector_type(4))) float f32x4;

template <int N> struct ic { static constexpr int v = N; };

#define WAITV(n) asm volatile("s_waitcnt vmcnt(" #n ")" ::: "memory")

__device__ __forceinline__ unsigned short f2bf(float f) {
  union { float f; uint32_t u; } v; v.f = f;
  uint32_t u = v.u;
  u += 0x7fffu + ((u >> 16) & 1u);   // round-to-nearest-even
  return (unsigned short)(u >> 16);
}

// ---------------- kernel 1: segment mean (seg_ids sorted) ----------------
__global__ __launch_bounds__(64) void k_segmean(
    const float* __restrict__ msg, const int* __restrict__ seg,
    unsigned short* __restrict__ means, int* __restrict__ counts)
{
  int node = blockIdx.x;
  int lane = threadIdx.x;

  int lo = 0, hi = N_MSG;
  while (lo < hi) { int m = (lo + hi) >> 1; if (seg[m] < node) lo = m + 1; else hi = m; }
  int start = lo;
  hi = N_MSG;
  while (lo < hi) { int m = (lo + hi) >> 1; if (seg[m] < node + 1) lo = m + 1; else hi = m; }
  int end = lo;
  int cnt = end - start;
  if (lane == 0) counts[node] = cnt;

  float4 s[5];
#pragma unroll
  for (int j = 0; j < 5; j++) s[j] = make_float4(0.f, 0.f, 0.f, 0.f);
  const float4* m4 = (const float4*)msg;   // 320 float4 per row
  for (int r = start; r < end; r++) {
#pragma unroll
    for (int j = 0; j < 5; j++) {
      float4 v = m4[r * 320 + j * 64 + lane];
      s[j].x += v.x; s[j].y += v.y; s[j].z += v.z; s[j].w += v.w;
    }
  }
  float inv = (cnt > 0) ? 1.0f / (float)cnt : 0.0f;
  ushort4* o4 = (ushort4*)means;
#pragma unroll
  for (int j = 0; j < 5; j++) {
    ushort4 o;
    o.x = f2bf(s[j].x * inv); o.y = f2bf(s[j].y * inv);
    o.z = f2bf(s[j].z * inv); o.w = f2bf(s[j].w * inv);
    o4[node * 320 + j * 64 + lane] = o;
  }
}

// ---------------- kernel 2: f32 -> bf16 cast ----------------
__global__ __launch_bounds__(256) void k_cvt(
    const float* __restrict__ in, unsigned short* __restrict__ out, int n4)
{
  int i = blockIdx.x * 256 + threadIdx.x;
  if (i >= n4) return;
  float4 v = ((const float4*)in)[i];
  ushort4 o;
  o.x = f2bf(v.x); o.y = f2bf(v.y); o.z = f2bf(v.z); o.w = f2bf(v.w);
  ((ushort4*)out)[i] = o;
}

// ---------------- kernel 3: fused GEMM (4 strips) + GRU epilogue ----------------
// 8-wave 128r x 64c tile (R6 geometry, proven coalesced) + 2-buffer LDS dbuf
// (80 KB = exactly 2 blocks/CU = 16 waves/CU) + prefetch-before-compute with
// counted vmcnt: stage(c+1) issued BEFORE compute(c); WAITV(5) confirms only
// chunk c (5 loads/wave stay in flight across the barrier); drain-to-0 only at
// the tail. Register discipline (R12 lesson: R7 sits exactly at the 128-reg /
// 4-wave-SIMD cliff): per-chunk address recompute (no persistent offsets),
// acc[4][4]=64 AGPR, launch_bounds(512,4) pins arch regs <= 64.
// Wave layout: wr=wid>>2 (2 row-groups of 64), wc=wid&3 (4 col-groups of 16).
// LDS layout (R6-proven): row-major [row][64k] + XOR swizzle gran^=(row&7);
// staging source permutes k-granule (csrc=(lane&7)^lrow) -> fully coalesced.
// 28 K-chunks: 0..19 = means@W_ih^T (K=1280), 20..27 = memb@W_hh^T (K=512).
__global__ __launch_bounds__(512, 4) void k_gru(
    const unsigned short* __restrict__ means, const unsigned short* __restrict__ memb,
    const unsigned short* __restrict__ wih,   const unsigned short* __restrict__ whh,
    const float* __restrict__ b_ih, const float* __restrict__ b_hh,
    const float* __restrict__ memory, const int* __restrict__ counts,
    float* __restrict__ out)
{
  __shared__ unsigned short Al[2][128 * 64];   // 2 x 16 KB
  __shared__ unsigned short Bl[2][192 * 64];   // 2 x 24 KB  (80 KB total)

  int tid = threadIdx.x;
  int lane = tid & 63, wid = tid >> 6;       // 8 waves
  int wr = wid >> 2, wc = wid & 3;           // 2 row-groups x 4 col-groups
  int row0 = blockIdx.y * 128;
  int c0 = blockIdx.x * 64;

  f32x4 acc[4][4];                            // [row-frag][strip]: r, z, i_n, h_n
#pragma unroll
  for (int f = 0; f < 4; f++)
#pragma unroll
    for (int s = 0; s < 4; s++) acc[f][s] = (f32x4)(0.f);

  int lrow = lane >> 3;                       // row-within-8 for staging
  int csrc = (lane & 7) ^ lrow;               // inverse-swizzled source k-granule

  // stage chunk c into dbuf pb (2 A-loads + 3 B-loads per wave; addresses
  // recomputed per chunk to keep persistent regs at zero)
  auto stage = [&](int c, int pb) {
    const unsigned short* Ag; const unsigned short* Bg; int ld, k0;
    if (c < 20) { Ag = means; Bg = wih; ld = DIM_MSG; k0 = c * 64; }
    else        { Ag = memb;  Bg = whh; ld = DIM_MEM; k0 = (c - 20) * 64; }
#pragma unroll
    for (int i = 0; i < 2; i++) {             // A: 8 rows per load (128 rows total)
      int rbase = (wid * 2 + i) * 8;
      int grow = row0 + rbase + lrow; if (grow > N_NODES - 1) grow = N_NODES - 1;
      const unsigned short* src = Ag + (size_t)grow * ld + k0 + csrc * 8;
      __builtin_amdgcn_global_load_lds(
          (const __attribute__((address_space(1))) void*)src,
          (__attribute__((address_space(3))) void*)&Al[pb][rbase * 64],
          16, 0, 0);
    }
#pragma unroll
    for (int i = 0; i < 3; i++) {             // B: 8 gate-cols per load (192 total)
      int gbase = (wid * 3 + i) * 8;
      int gcol = gbase + lrow;
      int st = gcol >> 6, col = gcol & 63;
      const unsigned short* src = Bg + (size_t)(st * 512 + c0 + col) * ld + k0 + csrc * 8;
      __builtin_amdgcn_global_load_lds(
          (const __attribute__((address_space(1))) void*)src,
          (__attribute__((address_space(3))) void*)&Bl[pb][gbase * 64],
          16, 0, 0);
    }
  };

  // compute chunk in dbuf pb; PH=0: strips {r,z,i_n}; PH=1: strips {r,z,h_n}
  auto compute = [&](int pb, auto PH) {
    constexpr int ph = decltype(PH)::v;
    int g = lane >> 4, r = lane & 15;
#pragma unroll
    for (int t = 0; t < 2; t++) {
      int c16 = t * 4 + g;
      int gr = c16 ^ (r & 7);
      bf16x8 a[4], b[3];
#pragma unroll
      for (int f = 0; f < 4; f++) {
        int row = wr * 64 + f * 16 + r;
        a[f] = *(const bf16x8*)&Al[pb][(row * 8 + gr) * 8];
      }
#pragma unroll
      for (int st = 0; st < 3; st++) {
        int gcol = st * 64 + wc * 16 + r;
        b[st] = *(const bf16x8*)&Bl[pb][(gcol * 8 + gr) * 8];
      }
#pragma unroll
      for (int f = 0; f < 4; f++)
#pragma unroll
        for (int st = 0; st < 3; st++) {
          constexpr int sm[2][3] = {{0, 1, 2}, {0, 1, 3}};
          acc[f][sm[ph][st]] = __builtin_amdgcn_mfma_f32_16x16x32_bf16(
              a[f], b[st], acc[f][sm[ph][st]], 0, 0, 0);
        }
    }
  };

  stage(0, 0);
  for (int c = 0; c < 28; ++c) {
    if (c < 27) { stage(c + 1, (c + 1) & 1); WAITV(5); }   // chunk c landed
    else        { WAITV(0); }
    __builtin_amdgcn_s_barrier();              // chunk c visible to all waves
    if (c < 20) compute(c & 1, ic<0>{});
    else        compute(c & 1, ic<1>{});
    __builtin_amdgcn_s_barrier();              // WAR: buffer c&1 free for c+2
  }

  // ---- GRU epilogue ----
  int cc = c0 + wc * 16 + (lane & 15);
  float br = b_ih[cc] + b_hh[cc];
  float bz = b_ih[512 + cc] + b_hh[512 + cc];
  float bin = b_ih[1024 + cc], bhn = b_hh[1024 + cc];
  int g = lane >> 4;
#pragma unroll
  for (int f = 0; f < 4; f++) {
    int rbase = row0 + wr * 64 + f * 16 + g * 4;
#pragma unroll
    for (int rr = 0; rr < 4; rr++) {
      int row = rbase + rr;
      if (row < N_NODES) {
        float rg = 1.f / (1.f + __expf(-(acc[f][0][rr] + br)));
        float zg = 1.f / (1.f + __expf(-(acc[f][1][rr] + bz)));
        float cd = tanhf(acc[f][2][rr] + bin + rg * (acc[f][3][rr] + bhn));
        float h = memory[(size_t)row * DIM_MEM + cc];
        float o = (counts[row] > 0) ? (1.f - zg) * cd + zg * h : h;
        out[(size_t)row * DIM_MEM + cc] = o;
      }
    }
  }
}

// ---------------- launch ----------------
extern "C" void kernel_launch(void* const* d_in, const int* in_sizes, int n_in,
                              void* d_out, int out_size, void* d_ws, size_t ws_size,
                              hipStream_t stream) {
  const float* msg  = (const float*)d_in[0];
  const int*   seg  = (const int*)d_in[1];
  const float* mem  = (const float*)d_in[2];
  const float* W_ih = (const float*)d_in[3];
  const float* W_hh = (const float*)d_in[4];
  const float* b_ih = (const float*)d_in[5];
  const float* b_hh = (const float*)d_in[6];
  float* out = (float*)d_out;

  char* ws = (char*)d_ws;
  unsigned short* means = (unsigned short*)(ws);                     // 128,000,000 B
  unsigned short* memb  = (unsigned short*)(ws + 128000000LL);       //  51,200,000 B
  unsigned short* wihb  = (unsigned short*)(ws + 179200000LL);       //   3,932,160 B
  unsigned short* whhb  = (unsigned short*)(ws + 183132160LL);       //   1,572,864 B
  int* counts           = (int*)(ws + 184705024LL);                  //     200,000 B

  k_segmean<<<N_NODES, 64, 0, stream>>>(msg, seg, means, counts);
  k_cvt<<<(N_NODES * DIM_MEM / 4 + 255) / 256, 256, 0, stream>>>(mem, memb, N_NODES * DIM_MEM / 4);
  k_cvt<<<(3 * DIM_MEM * DIM_MSG / 4 + 255) / 256, 256, 0, stream>>>(W_ih, wihb, 3 * DIM_MEM * DIM_MSG / 4);
  k_cvt<<<(3 * DIM_MEM * DIM_MEM / 4 + 255) / 256, 256, 0, stream>>>(W_hh, whhb, 3 * DIM_MEM * DIM_MEM / 4);

  dim3 grid(8, (N_NODES + 127) / 128, 1);   // blockIdx.x = col-tile (L2/XCD-aligned)
  k_gru<<<grid, 512, 0, stream>>>(means, memb, wihb, whhb, b_ih, b_hh, mem, counts, out);
}

// Round 14
// 559.362 us; speedup vs baseline: 4.5003x; 4.5003x over previous
//
#include <hip/hip_runtime.h>
#include <stdint.h>

#define N_NODES 50000
#define DIM_MEM 512
#define DIM_MSG 1280
#define N_MSG   100000

typedef __attribute__((ext_vector_type(8))) short bf16x8;
typedef __attribute__((ext_vector_type(4))) float f32x4;

template <int N> struct ic { static constexpr int v = N; };

__device__ __forceinline__ unsigned short f2bf(float f) {
  union { float f; uint32_t u; } v; v.f = f;
  uint32_t u = v.u;
  u += 0x7fffu + ((u >> 16) & 1u);   // round-to-nearest-even
  return (unsigned short)(u >> 16);
}

// ---------------- kernel 1: segment mean (seg_ids sorted) ----------------
__global__ __launch_bounds__(64) void k_segmean(
    const float* __restrict__ msg, const int* __restrict__ seg,
    unsigned short* __restrict__ means, int* __restrict__ counts)
{
  int node = blockIdx.x;
  int lane = threadIdx.x;

  int lo = 0, hi = N_MSG;
  while (lo < hi) { int m = (lo + hi) >> 1; if (seg[m] < node) lo = m + 1; else hi = m; }
  int start = lo;
  hi = N_MSG;
  while (lo < hi) { int m = (lo + hi) >> 1; if (seg[m] < node + 1) lo = m + 1; else hi = m; }
  int end = lo;
  int cnt = end - start;
  if (lane == 0) counts[node] = cnt;

  float4 s[5];
#pragma unroll
  for (int j = 0; j < 5; j++) s[j] = make_float4(0.f, 0.f, 0.f, 0.f);
  const float4* m4 = (const float4*)msg;   // 320 float4 per row
  for (int r = start; r < end; r++) {
#pragma unroll
    for (int j = 0; j < 5; j++) {
      float4 v = m4[r * 320 + j * 64 + lane];
      s[j].x += v.x; s[j].y += v.y; s[j].z += v.z; s[j].w += v.w;
    }
  }
  float inv = (cnt > 0) ? 1.0f / (float)cnt : 0.0f;
  ushort4* o4 = (ushort4*)means;
#pragma unroll
  for (int j = 0; j < 5; j++) {
    ushort4 o;
    o.x = f2bf(s[j].x * inv); o.y = f2bf(s[j].y * inv);
    o.z = f2bf(s[j].z * inv); o.w = f2bf(s[j].w * inv);
    o4[node * 320 + j * 64 + lane] = o;
  }
}

// ---------------- kernel 2: f32 -> bf16 cast ----------------
__global__ __launch_bounds__(256) void k_cvt(
    const float* __restrict__ in, unsigned short* __restrict__ out, int n4)
{
  int i = blockIdx.x * 256 + threadIdx.x;
  if (i >= n4) return;
  float4 v = ((const float4*)in)[i];
  ushort4 o;
  o.x = f2bf(v.x); o.y = f2bf(v.y); o.z = f2bf(v.z); o.w = f2bf(v.w);
  ((ushort4*)out)[i] = o;
}

// ---------------- kernel 3: fused GEMM (4 strips) + GRU epilogue ----------------
// R7-minimal structure (stateless staging, plain 2-barrier loop -- the ONLY
// structure that fits the 128-reg/4-wave budget; R8/R9/R13 all spilled) at
// R6's taller geometry to cut LDS traffic/FLOP (R7 is LDS-BW-bound at
// ~94 B/cyc: 88 KB per 1.57 MFLOP):
//   block = 128r x 64c, 512 thr / 8 waves; wave = 64r x 16c (wr=wid>>2,wc=wid&3)
//   B tile (24 KB) serves 128 rows -> 152 KB per 3.15 MFLOP = 48 KB/MFLOP (-15%)
//   LDS single-buffer 40 KB; regs 64+64 = 128 -> 2 blocks/CU = 16 waves/CU.
// acc strips {r=i_r+h_r, z=i_z+h_z, i_n, h_n}; r/z accumulate across phases.
// LDS layout (R6-proven): row-major [row][64k] + XOR swizzle gran^=(row&7);
// staging source permutes k-granule (csrc=(lane&7)^lrow) -> fully coalesced.
// 28 K-chunks: 0..19 = means@W_ih^T (K=1280), 20..27 = memb@W_hh^T (K=512).
__global__ __launch_bounds__(512, 4) void k_gru(
    const unsigned short* __restrict__ means, const unsigned short* __restrict__ memb,
    const unsigned short* __restrict__ wih,   const unsigned short* __restrict__ whh,
    const float* __restrict__ b_ih, const float* __restrict__ b_hh,
    const float* __restrict__ memory, const int* __restrict__ counts,
    float* __restrict__ out)
{
  __shared__ unsigned short Al[128 * 64];   // 16 KB
  __shared__ unsigned short Bl[192 * 64];   // 24 KB

  int tid = threadIdx.x;
  int lane = tid & 63, wid = tid >> 6;       // 8 waves
  int wr = wid >> 2, wc = wid & 3;           // 2 row-groups x 4 col-groups
  int row0 = blockIdx.y * 128;
  int c0 = blockIdx.x * 64;

  f32x4 acc[4][4];                            // [row-frag][strip]: r, z, i_n, h_n
#pragma unroll
  for (int f = 0; f < 4; f++)
#pragma unroll
    for (int s = 0; s < 4; s++) acc[f][s] = (f32x4)(0.f);

  int lrow = lane >> 3;                       // row-within-8 for staging
  int csrc = (lane & 7) ^ lrow;               // inverse-swizzled source k-granule

  // stage chunk c (2 A-loads + 3 B-loads per wave; stateless recompute)
  auto stage = [&](int c) {
    const unsigned short* Ag; const unsigned short* Bg; int ld, k0;
    if (c < 20) { Ag = means; Bg = wih; ld = DIM_MSG; k0 = c * 64; }
    else        { Ag = memb;  Bg = whh; ld = DIM_MEM; k0 = (c - 20) * 64; }
#pragma unroll
    for (int i = 0; i < 2; i++) {             // A: 8 rows per load (128 rows)
      int rbase = (wid * 2 + i) * 8;
      int grow = row0 + rbase + lrow; if (grow > N_NODES - 1) grow = N_NODES - 1;
      const unsigned short* src = Ag + (size_t)grow * ld + k0 + csrc * 8;
      __builtin_amdgcn_global_load_lds(
          (const __attribute__((address_space(1))) void*)src,
          (__attribute__((address_space(3))) void*)&Al[rbase * 64],
          16, 0, 0);
    }
#pragma unroll
    for (int i = 0; i < 3; i++) {             // B: 8 gate-cols per load (192)
      int gbase = (wid * 3 + i) * 8;
      int gcol = gbase + lrow;
      int st = gcol >> 6, col = gcol & 63;
      const unsigned short* src = Bg + (size_t)(st * 512 + c0 + col) * ld + k0 + csrc * 8;
      __builtin_amdgcn_global_load_lds(
          (const __attribute__((address_space(1))) void*)src,
          (__attribute__((address_space(3))) void*)&Bl[gbase * 64],
          16, 0, 0);
    }
  };

  // compute current chunk; PH=0: strips {r,z,i_n}; PH=1: strips {r,z,h_n}
  auto compute = [&](auto PH) {
    constexpr int ph = decltype(PH)::v;
    int g = lane >> 4, r = lane & 15;
#pragma unroll
    for (int t = 0; t < 2; t++) {
      int c16 = t * 4 + g;
      int gr = c16 ^ (r & 7);
      bf16x8 a[4], b[3];
#pragma unroll
      for (int f = 0; f < 4; f++) {
        int row = wr * 64 + f * 16 + r;
        a[f] = *(const bf16x8*)&Al[(row * 8 + gr) * 8];
      }
#pragma unroll
      for (int st = 0; st < 3; st++) {
        int gcol = st * 64 + wc * 16 + r;
        b[st] = *(const bf16x8*)&Bl[(gcol * 8 + gr) * 8];
      }
#pragma unroll
      for (int f = 0; f < 4; f++)
#pragma unroll
        for (int st = 0; st < 3; st++) {
          constexpr int sm[2][3] = {{0, 1, 2}, {0, 1, 3}};
          acc[f][sm[ph][st]] = __builtin_amdgcn_mfma_f32_16x16x32_bf16(
              a[f], b[st], acc[f][sm[ph][st]], 0, 0, 0);
        }
    }
  };

  for (int c = 0; c < 20; ++c) {              // phase 1: r+=, z+=, i_n
    stage(c);
    __syncthreads();
    compute(ic<0>{});
    __syncthreads();
  }
  for (int c = 20; c < 28; ++c) {             // phase 2: r+=, z+=, h_n
    stage(c);
    __syncthreads();
    compute(ic<1>{});
    __syncthreads();
  }

  // ---- GRU epilogue ----
  int cc = c0 + wc * 16 + (lane & 15);
  float br = b_ih[cc] + b_hh[cc];
  float bz = b_ih[512 + cc] + b_hh[512 + cc];
  float bin = b_ih[1024 + cc], bhn = b_hh[1024 + cc];
  int g = lane >> 4;
#pragma unroll
  for (int f = 0; f < 4; f++) {
    int rbase = row0 + wr * 64 + f * 16 + g * 4;
#pragma unroll
    for (int rr = 0; rr < 4; rr++) {
      int row = rbase + rr;
      if (row < N_NODES) {
        float rg = 1.f / (1.f + __expf(-(acc[f][0][rr] + br)));
        float zg = 1.f / (1.f + __expf(-(acc[f][1][rr] + bz)));
        float cd = tanhf(acc[f][2][rr] + bin + rg * (acc[f][3][rr] + bhn));
        float h = memory[(size_t)row * DIM_MEM + cc];
        float o = (counts[row] > 0) ? (1.f - zg) * cd + zg * h : h;
        out[(size_t)row * DIM_MEM + cc] = o;
      }
    }
  }
}

// ---------------- launch ----------------
extern "C" void kernel_launch(void* const* d_in, const int* in_sizes, int n_in,
                              void* d_out, int out_size, void* d_ws, size_t ws_size,
                              hipStream_t stream) {
  const float* msg  = (const float*)d_in[0];
  const int*   seg  = (const int*)d_in[1];
  const float* mem  = (const float*)d_in[2];
  const float* W_ih = (const float*)d_in[3];
  const float* W_hh = (const float*)d_in[4];
  const float* b_ih = (const float*)d_in[5];
  const float* b_hh = (const float*)d_in[6];
  float* out = (float*)d_out;

  char* ws = (char*)d_ws;
  unsigned short* means = (unsigned short*)(ws);                     // 128,000,000 B
  unsigned short* memb  = (unsigned short*)(ws + 128000000LL);       //  51,200,000 B
  unsigned short* wihb  = (unsigned short*)(ws + 179200000LL);       //   3,932,160 B
  unsigned short* whhb  = (unsigned short*)(ws + 183132160LL);       //   1,572,864 B
  int* counts           = (int*)(ws + 184705024LL);                  //     200,000 B

  k_segmean<<<N_NODES, 64, 0, stream>>>(msg, seg, means, counts);
  k_cvt<<<(N_NODES * DIM_MEM / 4 + 255) / 256, 256, 0, stream>>>(mem, memb, N_NODES * DIM_MEM / 4);
  k_cvt<<<(3 * DIM_MEM * DIM_MSG / 4 + 255) / 256, 256, 0, stream>>>(W_ih, wihb, 3 * DIM_MEM * DIM_MSG / 4);
  k_cvt<<<(3 * DIM_MEM * DIM_MEM / 4 + 255) / 256, 256, 0, stream>>>(W_hh, whhb, 3 * DIM_MEM * DIM_MEM / 4);

  dim3 grid(8, (N_NODES + 127) / 128, 1);   // blockIdx.x = col-tile (L2/XCD-aligned)
  k_gru<<<grid, 512, 0, stream>>>(means, memb, wihb, whhb, b_ih, b_hh, mem, counts, out);
}

// Round 15
// 557.033 us; speedup vs baseline: 4.5192x; 1.0042x over previous
//
#include <hip/hip_runtime.h>
#include <stdint.h>

#define N_NODES 50000
#define DIM_MEM 512
#define DIM_MSG 1280
#define N_MSG   100000

typedef __attribute__((ext_vector_type(8))) short bf16x8;
typedef __attribute__((ext_vector_type(4))) float f32x4;

template <int N> struct ic { static constexpr int v = N; };

__device__ __forceinline__ unsigned short f2bf(float f) {
  union { float f; uint32_t u; } v; v.f = f;
  uint32_t u = v.u;
  u += 0x7fffu + ((u >> 16) & 1u);   // round-to-nearest-even
  return (unsigned short)(u >> 16);
}

// ---------------- kernel 1: segment mean + fused memory->bf16 cvt ----------------
// one 64-lane block per node; binary search for row range; f32 sums -> bf16
// means; also converts this node's memory row (512 f32 -> bf16) into memb.
__global__ __launch_bounds__(64) void k_segmean(
    const float* __restrict__ msg, const int* __restrict__ seg,
    const float* __restrict__ memory,
    unsigned short* __restrict__ means, unsigned short* __restrict__ memb,
    int* __restrict__ counts)
{
  int node = blockIdx.x;
  int lane = threadIdx.x;

  int lo = 0, hi = N_MSG;
  while (lo < hi) { int m = (lo + hi) >> 1; if (seg[m] < node) lo = m + 1; else hi = m; }
  int start = lo;
  hi = N_MSG;
  while (lo < hi) { int m = (lo + hi) >> 1; if (seg[m] < node + 1) lo = m + 1; else hi = m; }
  int end = lo;
  int cnt = end - start;
  if (lane == 0) counts[node] = cnt;

  // fused: convert memory row (512 f32 = 2 float4/lane) to bf16
  {
    const float4* mrow = (const float4*)(memory + (size_t)node * DIM_MEM);
    ushort4* orow = (ushort4*)(memb + (size_t)node * DIM_MEM);
#pragma unroll
    for (int j = 0; j < 2; j++) {
      float4 v = mrow[j * 64 + lane];
      ushort4 o;
      o.x = f2bf(v.x); o.y = f2bf(v.y); o.z = f2bf(v.z); o.w = f2bf(v.w);
      orow[j * 64 + lane] = o;
    }
  }

  float4 s[5];
#pragma unroll
  for (int j = 0; j < 5; j++) s[j] = make_float4(0.f, 0.f, 0.f, 0.f);
  const float4* m4 = (const float4*)msg;   // 320 float4 per row
  for (int r = start; r < end; r++) {
#pragma unroll
    for (int j = 0; j < 5; j++) {
      float4 v = m4[r * 320 + j * 64 + lane];
      s[j].x += v.x; s[j].y += v.y; s[j].z += v.z; s[j].w += v.w;
    }
  }
  float inv = (cnt > 0) ? 1.0f / (float)cnt : 0.0f;
  ushort4* o4 = (ushort4*)means;
#pragma unroll
  for (int j = 0; j < 5; j++) {
    ushort4 o;
    o.x = f2bf(s[j].x * inv); o.y = f2bf(s[j].y * inv);
    o.z = f2bf(s[j].z * inv); o.w = f2bf(s[j].w * inv);
    o4[node * 320 + j * 64 + lane] = o;
  }
}

// ---------------- kernel 2: f32 -> bf16 cast for BOTH weight matrices ----------------
#define N4_IH (3 * DIM_MEM * DIM_MSG / 4)   // 491520
#define N4_HH (3 * DIM_MEM * DIM_MEM / 4)   // 196608
__global__ __launch_bounds__(256) void k_cvtw(
    const float* __restrict__ wih, const float* __restrict__ whh,
    unsigned short* __restrict__ wihb, unsigned short* __restrict__ whhb)
{
  int i = blockIdx.x * 256 + threadIdx.x;
  const float4* src; ushort4* dst; int idx;
  if (i < N4_IH) { src = (const float4*)wih; dst = (ushort4*)wihb; idx = i; }
  else if (i < N4_IH + N4_HH) { src = (const float4*)whh; dst = (ushort4*)whhb; idx = i - N4_IH; }
  else return;
  float4 v = src[idx];
  ushort4 o;
  o.x = f2bf(v.x); o.y = f2bf(v.y); o.z = f2bf(v.z); o.w = f2bf(v.w);
  dst[idx] = o;
}

// ---------------- kernel 3: fused GEMM (4 strips) + GRU epilogue ----------------
// EXACT R7 structure (best measured: 402 us, VGPR 64+64=128, zero spill) with
// launch_bounds(256,4): 128 regs/thread admits 4 blocks/CU (4x32KB LDS=128KB).
// Geometry: 256 thr / 4 waves; tile 64r x 64c; wave = 64r x 16c x 3 strips;
// acc[4][4] = 64 f32 {r=i_r+h_r, z=i_z+h_z, i_n, h_n}; single-buffer 32 KB LDS;
// plain 2-barrier loop (every pipelining variant spilled or lost occupancy:
// R8/R9/R12/R13). Per-wave (Mw,Nw)=(64,16) minimizes ds_reads at acc=64.
// LDS layout (R6): row-major [row][64k] + XOR swizzle gran^=(row&7); staging
// source permutes k-granule (csrc=(lane&7)^lrow) -> fully coalesced.
// 28 K-chunks: 0..19 = means@W_ih^T (K=1280), 20..27 = memb@W_hh^T (K=512).
__global__ __launch_bounds__(256, 4) void k_gru(
    const unsigned short* __restrict__ means, const unsigned short* __restrict__ memb,
    const unsigned short* __restrict__ wih,   const unsigned short* __restrict__ whh,
    const float* __restrict__ b_ih, const float* __restrict__ b_hh,
    const float* __restrict__ memory, const int* __restrict__ counts,
    float* __restrict__ out)
{
  __shared__ unsigned short Al[64 * 64];    // 8 KB
  __shared__ unsigned short Bl[192 * 64];   // 24 KB

  int tid = threadIdx.x;
  int lane = tid & 63, wid = tid >> 6;       // 4 waves
  int wc = wid;                               // col-group 0..3
  int row0 = blockIdx.y * 64;
  int c0 = blockIdx.x * 64;

  f32x4 acc[4][4];                            // [row-frag][strip]: r, z, i_n, h_n
#pragma unroll
  for (int f = 0; f < 4; f++)
#pragma unroll
    for (int s = 0; s < 4; s++) acc[f][s] = (f32x4)(0.f);

  int lrow = lane >> 3;                       // row-within-8 for staging
  int csrc = (lane & 7) ^ lrow;               // inverse-swizzled source k-granule

  // stage chunk c (2 A-loads + 6 B-loads per wave; stateless recompute)
  auto stage = [&](int c) {
    const unsigned short* Ag; const unsigned short* Bg; int ld, k0;
    if (c < 20) { Ag = means; Bg = wih; ld = DIM_MSG; k0 = c * 64; }
    else        { Ag = memb;  Bg = whh; ld = DIM_MEM; k0 = (c - 20) * 64; }
#pragma unroll
    for (int i = 0; i < 2; i++) {             // A: 8 rows per load
      int rbase = (wid * 2 + i) * 8;
      int grow = row0 + rbase + lrow; if (grow > N_NODES - 1) grow = N_NODES - 1;
      const unsigned short* src = Ag + (size_t)grow * ld + k0 + csrc * 8;
      __builtin_amdgcn_global_load_lds(
          (const __attribute__((address_space(1))) void*)src,
          (__attribute__((address_space(3))) void*)&Al[rbase * 64],
          16, 0, 0);
    }
#pragma unroll
    for (int i = 0; i < 6; i++) {             // B: 8 gate-cols per load
      int gbase = (wid * 6 + i) * 8;
      int gcol = gbase + lrow;                // 0..191
      int st = gcol >> 6, col = gcol & 63;
      const unsigned short* src = Bg + (size_t)(st * 512 + c0 + col) * ld + k0 + csrc * 8;
      __builtin_amdgcn_global_load_lds(
          (const __attribute__((address_space(1))) void*)src,
          (__attribute__((address_space(3))) void*)&Bl[gbase * 64],
          16, 0, 0);
    }
  };

  // compute current chunk; PH=0: strips {0,1,2}; PH=1: strips {0,1,3}
  auto compute = [&](auto PH) {
    constexpr int ph = decltype(PH)::v;
    int g = lane >> 4, r = lane & 15;
#pragma unroll
    for (int t = 0; t < 2; t++) {
      int c16 = t * 4 + g;
      int gr = c16 ^ (r & 7);
      bf16x8 a[4], b[3];
#pragma unroll
      for (int f = 0; f < 4; f++) {
        int row = f * 16 + r;
        a[f] = *(const bf16x8*)&Al[(row * 8 + gr) * 8];
      }
#pragma unroll
      for (int st = 0; st < 3; st++) {
        int gcol = st * 64 + wc * 16 + r;
        b[st] = *(const bf16x8*)&Bl[(gcol * 8 + gr) * 8];
      }
#pragma unroll
      for (int f = 0; f < 4; f++)
#pragma unroll
        for (int st = 0; st < 3; st++) {
          constexpr int sm[2][3] = {{0, 1, 2}, {0, 1, 3}};
          acc[f][sm[ph][st]] = __builtin_amdgcn_mfma_f32_16x16x32_bf16(
              a[f], b[st], acc[f][sm[ph][st]], 0, 0, 0);
        }
    }
  };

  for (int c = 0; c < 20; ++c) {              // phase 1: r+=, z+=, i_n
    stage(c);
    __syncthreads();
    compute(ic<0>{});
    __syncthreads();
  }
  for (int c = 20; c < 28; ++c) {             // phase 2: r+=, z+=, h_n
    stage(c);
    __syncthreads();
    compute(ic<1>{});
    __syncthreads();
  }

  // ---- GRU epilogue ----
  int cc = c0 + wc * 16 + (lane & 15);
  float br = b_ih[cc] + b_hh[cc];
  float bz = b_ih[512 + cc] + b_hh[512 + cc];
  float bin = b_ih[1024 + cc], bhn = b_hh[1024 + cc];
  int g = lane >> 4;
#pragma unroll
  for (int f = 0; f < 4; f++) {
    int rbase = row0 + f * 16 + g * 4;
#pragma unroll
    for (int rr = 0; rr < 4; rr++) {
      int row = rbase + rr;
      if (row < N_NODES) {
        float rg = 1.f / (1.f + __expf(-(acc[f][0][rr] + br)));
        float zg = 1.f / (1.f + __expf(-(acc[f][1][rr] + bz)));
        float cd = tanhf(acc[f][2][rr] + bin + rg * (acc[f][3][rr] + bhn));
        float h = memory[(size_t)row * DIM_MEM + cc];
        float o = (counts[row] > 0) ? (1.f - zg) * cd + zg * h : h;
        out[(size_t)row * DIM_MEM + cc] = o;
      }
    }
  }
}

// ---------------- launch ----------------
extern "C" void kernel_launch(void* const* d_in, const int* in_sizes, int n_in,
                              void* d_out, int out_size, void* d_ws, size_t ws_size,
                              hipStream_t stream) {
  const float* msg  = (const float*)d_in[0];
  const int*   seg  = (const int*)d_in[1];
  const float* mem  = (const float*)d_in[2];
  const float* W_ih = (const float*)d_in[3];
  const float* W_hh = (const float*)d_in[4];
  const float* b_ih = (const float*)d_in[5];
  const float* b_hh = (const float*)d_in[6];
  float* out = (float*)d_out;

  char* ws = (char*)d_ws;
  unsigned short* means = (unsigned short*)(ws);                     // 128,000,000 B
  unsigned short* memb  = (unsigned short*)(ws + 128000000LL);       //  51,200,000 B
  unsigned short* wihb  = (unsigned short*)(ws + 179200000LL);       //   3,932,160 B
  unsigned short* whhb  = (unsigned short*)(ws + 183132160LL);       //   1,572,864 B
  int* counts           = (int*)(ws + 184705024LL);                  //     200,000 B

  k_segmean<<<N_NODES, 64, 0, stream>>>(msg, seg, mem, means, memb, counts);
  k_cvtw<<<(N4_IH + N4_HH + 255) / 256, 256, 0, stream>>>(W_ih, W_hh, wihb, whhb);

  dim3 grid(8, (N_NODES + 63) / 64, 1);   // blockIdx.x = col-tile (L2/XCD-aligned)
  k_gru<<<grid, 256, 0, stream>>>(means, memb, wihb, whhb, b_ih, b_hh, mem, counts, out);
}